// Round 14
// baseline (318.970 us; speedup 1.0000x reference)
//
#include <hip/hip_runtime.h>

// Problem constants (fixed by reference setup_inputs)
#define N_NODES  65536
#define D_FEAT   256
#define N_GRAPHS 256
#define NPG      256      // nodes per graph
#define N_EDGES  524288
#define CAP      2560     // support cap (true max = 2048 edges + 256 diag = 2304)
#define EPSF     0.1f
#define MAXIT    100
#define KMAX     4        // register slots per sub-thread; 4 subs -> 16/row
#define LOG2E_F  1.4426950408889634f
#define LN2_F    0.6931471805599453f
#define CSCALE   (10.0f * LOG2E_F)   // C * (1/eps) * log2(e)  -> base-2 domain
#define MU_VAL   (1.0f / 256.0f + 1e-8f)

// dynamic LDS for k_prep: tgtb (256 rows x 512 B bf16) = 131072 B.
// phase-A scratch (m: 8 KB, sc: 1 KB) aliases into it.
#define DYN_SIZE  131072

__device__ __forceinline__ float waveReduceSum(float v){
  for (int o = 32; o; o >>= 1) v += __shfl_down(v, o);
  return v;
}

// ---- DPP helpers (VALU pipe; verified on HW R10-R13) ----
template<int CTRL>
__device__ __forceinline__ float fdpp(float x){
  int xi = __float_as_int(x);
  int i = __builtin_amdgcn_update_dpp(xi, xi, CTRL, 0xf, 0xf, true);
  return __int_as_float(i);
}
__device__ __forceinline__ float dppSum64(float x){
  x += fdpp<0x111>(x);   // row_shr:1
  x += fdpp<0x112>(x);   // row_shr:2
  x += fdpp<0x114>(x);   // row_shr:4
  x += fdpp<0x118>(x);   // row_shr:8
  x += fdpp<0x142>(x);   // row_bcast:15
  x += fdpp<0x143>(x);   // row_bcast:31
  return x;
}
__device__ __forceinline__ float bcast63(float x){
  return __int_as_float(__builtin_amdgcn_readlane(__float_as_int(x), 63));
}
#define QXOR1 0xB1   // quad_perm [1,0,3,2]
#define QXOR2 0x4E   // quad_perm [2,3,0,1]

// round-to-nearest-even f32 -> bf16 (as u16 in low bits)
__device__ __forceinline__ unsigned bf16r(float f){
  unsigned u = __float_as_uint(f);
  return (u + 0x7FFFu + ((u >> 16) & 1u)) >> 16;
}

// -------- scatter edges + diagonal into per-graph bitmask --------
__global__ __launch_bounds__(256) void k_scatter(const int* __restrict__ ei,
                                                 unsigned* __restrict__ bm){
  int t = blockIdx.x * 256 + threadIdx.x;
  if (t < N_EDGES){
    int uu = ei[t], vv = ei[N_EDGES + t];
    int b = uu >> 8;            // batch = node / 256 (equal-size graphs)
    int r = uu & 255;
    int c = vv & 255;
    atomicOr(&bm[(size_t)b * 2048 + r * 8 + (c >> 5)], 1u << (c & 31));
  } else {
    int i = t - N_EDGES;
    if (i < N_NODES){
      int b = i >> 8; int p = i & 255;
      atomicOr(&bm[(size_t)b * 2048 + p * 8 + (p >> 5)], 1u << (p & 31));
    }
  }
}

// ==================== k_prep: structure + costs (phases A-C) ====================
// A: CSR/CSC structure in LDS   B: tgt -> normalized bf16 in LDS (dynamic)
// C: sparse cosine costs from LDS rows   then write everything to global.
__global__ __launch_bounds__(1024) void k_prep(
    const unsigned* __restrict__ bm,
    const float* __restrict__ src, const float* __restrict__ tgt,
    float* __restrict__ gvals, unsigned char* __restrict__ gcols,
    unsigned char* __restrict__ grows, unsigned short* __restrict__ gcidx,
    int* __restrict__ grp, int* __restrict__ gcp)
{
  __shared__ float          cs[CAP];
  __shared__ unsigned short ents[CAP];
  __shared__ unsigned short cidx[CAP];
  __shared__ int            rp[257], cp[257];
  extern __shared__ char    dyn[];
  uint2*    tgtb = (uint2*)dyn;             // 256 rows x 64 uint2 (phases B/C)
  unsigned* m    = (unsigned*)dyn;          // phase-A alias
  int*      sc   = (int*)(dyn + 8192);      // phase-A alias

  int g = blockIdx.x, tid = threadIdx.x;
  int lane = tid & 63, wid = tid >> 6;

  // ---------- Phase A: structure ----------
  for (int i = tid; i < 2048; i += 1024) m[i] = bm[(size_t)g * 2048 + i];
  __syncthreads();

  int nnz = 0;
  if (tid < 256){
    #pragma unroll
    for (int w = 0; w < 8; w++) nnz += __popc(m[tid * 8 + w]);
    sc[tid] = nnz;
  }
  __syncthreads();
  for (int o = 1; o < 256; o <<= 1){
    int t = (tid < 256 && tid >= o) ? sc[tid - o] : 0;
    __syncthreads();
    if (tid < 256) sc[tid] += t;
    __syncthreads();
  }
  if (tid < 256){
    rp[tid] = sc[tid] - nnz;
    if (tid == 255) rp[256] = (sc[255] > CAP ? CAP : sc[255]);
  }
  __syncthreads();

  if (tid < 256){
    int k = rp[tid];
    #pragma unroll
    for (int w = 0; w < 8; w++){
      unsigned bits = m[tid * 8 + w];
      while (bits){
        int b = __ffs(bits) - 1; bits &= bits - 1;
        if (k < CAP) ents[k] = (unsigned short)((tid << 8) | (w * 32 + b));
        k++;
      }
    }
  }
  __syncthreads();

  int cn = 0, cw_ = 0; unsigned cb_ = 0;
  if (tid < 256){
    cw_ = tid >> 5; cb_ = 1u << (tid & 31);
    for (int r = 0; r < 256; r++) cn += (m[r * 8 + cw_] & cb_) ? 1 : 0;
    sc[tid] = cn;
  }
  __syncthreads();
  for (int o = 1; o < 256; o <<= 1){
    int t = (tid < 256 && tid >= o) ? sc[tid - o] : 0;
    __syncthreads();
    if (tid < 256) sc[tid] += t;
    __syncthreads();
  }
  if (tid < 256){
    cp[tid] = sc[tid] - cn;
    if (tid == 255) cp[256] = (sc[255] > CAP ? CAP : sc[255]);
  }
  __syncthreads();
  if (tid < 256){
    int kk = cp[tid];
    for (int r = 0; r < 256; r++){
      if (m[r * 8 + cw_] & cb_){
        int idx = rp[r];
        #pragma unroll
        for (int w = 0; w < 8; w++){
          unsigned mm2 = m[r * 8 + w];
          if (w < cw_) idx += __popc(mm2);
          else if (w == cw_) idx += __popc(mm2 & (cb_ - 1u));
        }
        if (kk < CAP && idx < CAP) cidx[kk] = (unsigned short)idx;
        kk++;
      }
    }
  }
  __syncthreads();   // m/sc dead; tgtb region free

  // ---------- Phase B: tgt rows -> normalized bf16 in LDS ----------
  const float4* tbase = reinterpret_cast<const float4*>(tgt + (size_t)g * NPG * D_FEAT);
  const float4* sbase = reinterpret_cast<const float4*>(src + (size_t)g * NPG * D_FEAT);
  for (int r = wid; r < 256; r += 16){
    float4 x = tbase[r * 64 + lane];
    float s = x.x*x.x + x.y*x.y + x.z*x.z + x.w*x.w;
    float inv = 1.0f / (sqrtf(bcast63(dppSum64(s))) + 1e-12f);
    unsigned p0 = bf16r(x.x * inv) | (bf16r(x.y * inv) << 16);
    unsigned p1 = bf16r(x.z * inv) | (bf16r(x.w * inv) << 16);
    tgtb[r * 64 + lane] = make_uint2(p0, p1);
  }
  __syncthreads();

  // ---------- Phase C: sparse cosine costs from LDS ----------
  for (int r = wid; r < 256; r += 16){
    int rs = rp[r], re = rp[r + 1];        // re > rs (self-loop diag)
    float4 A4 = sbase[r * 64 + lane];
    float s2 = A4.x*A4.x + A4.y*A4.y + A4.z*A4.z + A4.w*A4.w;
    float ai = 1.0f / (sqrtf(bcast63(dppSum64(s2))) + 1e-12f);
    A4.x *= ai; A4.y *= ai; A4.z *= ai; A4.w *= ai;
    for (int e0 = rs; e0 < re; e0 += 8){
      int idx[8];
      #pragma unroll
      for (int i = 0; i < 8; i++){
        int e = e0 + i; if (e >= re) e = re - 1;
        idx[i] = ents[e] & 255;
      }
      uint2 w[8];
      #pragma unroll
      for (int i = 0; i < 8; i++) w[i] = tgtb[idx[i] * 64 + lane];
      float d[8];
      #pragma unroll
      for (int i = 0; i < 8; i++){
        float f0 = __uint_as_float(w[i].x << 16);
        float f1 = __uint_as_float(w[i].x & 0xFFFF0000u);
        float f2 = __uint_as_float(w[i].y << 16);
        float f3 = __uint_as_float(w[i].y & 0xFFFF0000u);
        d[i] = A4.x*f0 + A4.y*f1 + A4.z*f2 + A4.w*f3;
      }
      #pragma unroll
      for (int i = 0; i < 8; i++) d[i] = dppSum64(d[i]);
      if (lane == 63){
        #pragma unroll
        for (int i = 0; i < 8; i++){
          if (e0 + i < re) cs[e0 + i] = (1.0f - d[i]) * CSCALE;
        }
      }
    }
  }
  __syncthreads();

  // ---------- write out structure + costs ----------
  int total = rp[256];
  size_t base = (size_t)g * CAP;
  for (int e = tid; e < total; e += 1024){
    gvals[base + e] = cs[e];
    gcols[base + e] = (unsigned char)(ents[e] & 255);
    grows[base + e] = (unsigned char)(ents[e] >> 8);
    gcidx[base + e] = cidx[e];
  }
  if (tid < 257){
    grp[g * 257 + tid] = rp[tid];
    gcp[g * 257 + tid] = cp[tid];
  }
}

// ==================== k_sink: verbatim R9 winner (115 us) ====================
// Multiplicative domain: LDS holds A_r = 2^alpha, B_c = 2^beta. Registers
// hold w_e = 2^(-c2_e) (loop-invariant).
//   A_new_r = MU / sum_j B_j * w_rj ; B_new_c = MU / sum_i A_new_i * w_ic
// alpha recovered per row via native v_log_f32 for err. Lazy wd in row pass.
__global__ __launch_bounds__(1024) void k_sink(
    const float* __restrict__ gvals, const unsigned char* __restrict__ gcols,
    const unsigned char* __restrict__ grows, const unsigned short* __restrict__ gcidx,
    const int* __restrict__ grp, const int* __restrict__ gcp,
    float* __restrict__ err_ws, float* __restrict__ wd_ws)
{
  __shared__ float su[256], sv[256], drow[256], wrow[256];
  __shared__ float sErr[MAXIT], sWd[MAXIT];
  int g = blockIdx.x, tid = threadIdx.x;
  int row = tid >> 2, sub = tid & 3;
  size_t base = (size_t)g * CAP;

  // --- prefetch row-side entries: col id, w=2^-c2, c2 (wd weight) ---
  int rs = grp[g * 257 + row], re = grp[g * 257 + row + 1];
  int rcol[KMAX]; float rw[KMAX], rc2[KMAX];
  #pragma unroll
  for (int k = 0; k < KMAX; k++){
    int idx = rs + sub + 4 * k;
    bool v = idx < re;
    int ai = v ? idx : 0;
    rcol[k] = v ? (int)gcols[base + ai] : 0;
    float c2 = v ? gvals[base + ai] : 0.f;
    rw[k]  = v ? exp2f(-c2) : 0.f;     // invalid -> contributes exactly 0
    rc2[k] = c2;
  }
  int rOv = rs + sub + 4 * KMAX;

  // --- prefetch col-side entries (resolve gcidx indirection once) ---
  int cs0 = gcp[g * 257 + row], ce = gcp[g * 257 + row + 1];
  int crow[KMAX]; float cw[KMAX];
  #pragma unroll
  for (int k = 0; k < KMAX; k++){
    int idx = cs0 + sub + 4 * k;
    bool v = idx < ce;
    int ai = v ? idx : 0;
    int e = v ? (int)gcidx[base + ai] : 0;
    crow[k] = v ? (int)grows[base + e] : 0;
    cw[k]   = v ? exp2f(-gvals[base + e]) : 0.f;
  }
  int cOv = cs0 + sub + 4 * KMAX;

  if (tid < 256){ su[tid] = 1.f; sv[tid] = 1.f; }   // 2^0
  __syncthreads();

  const float LOG2_MU = log2f(MU_VAL);
  float a = 0.f, Aprev = 1.f;

  for (int it = 0; it < MAXIT; ++it){
    // ---- row pass: sm = sum B*w ----
    float x0 = sv[rcol[0]] * rw[0];
    float x1 = sv[rcol[1]] * rw[1];
    float x2 = sv[rcol[2]] * rw[2];
    float x3 = sv[rcol[3]] * rw[3];
    float sm   = x0 + x1 + x2 + x3;
    float wsum = x0*rc2[0] + x1*rc2[1] + x2*rc2[2] + x3*rc2[3];
    for (int idx = rOv; idx < re; idx += 4){      // rare overflow rows
      float cv = gvals[base + idx];
      float xo = sv[gcols[base + idx]] * exp2f(-cv);
      sm += xo; wsum += xo * cv;
    }
    sm   += fdpp<QXOR1>(sm);   sm   += fdpp<QXOR2>(sm);
    wsum += fdpp<QXOR1>(wsum); wsum += fdpp<QXOR2>(wsum);
    float Anew = MU_VAL * __builtin_amdgcn_rcpf(sm);
    float an   = LOG2_MU - __builtin_amdgcn_logf(sm);
    if (sub == 0){
      su[row]   = Anew;
      drow[row] = fabsf(an - a);
      wrow[row] = Aprev * wsum;    // wd contribution of iter it-1
    }
    a = an; Aprev = Anew;
    __syncthreads();   // B1 (LDS only)

    // single-wave graph-scalar reductions into LDS histories
    if (tid < 64){
      float e4 = drow[tid] + drow[tid + 64] + drow[tid + 128] + drow[tid + 192];
      e4 = waveReduceSum(e4);
      if (tid == 0) sErr[it] = e4 * (EPSF * LN2_F);
    } else if (tid < 128 && it > 0){
      int l = tid - 64;
      float w4 = wrow[l] + wrow[l + 64] + wrow[l + 128] + wrow[l + 192];
      w4 = waveReduceSum(w4);
      if (l == 0) sWd[it - 1] = w4 * (EPSF * LN2_F);
    }

    // ---- col pass: csm = sum A_new * w ----
    float y0 = su[crow[0]] * cw[0];
    float y1 = su[crow[1]] * cw[1];
    float y2 = su[crow[2]] * cw[2];
    float y3 = su[crow[3]] * cw[3];
    float csm = y0 + y1 + y2 + y3;
    for (int idx = cOv; idx < ce; idx += 4){      // rare overflow cols
      int e = gcidx[base + idx];
      csm += su[grows[base + e]] * exp2f(-gvals[base + e]);
    }
    csm += fdpp<QXOR1>(csm); csm += fdpp<QXOR2>(csm);
    float Bnew = MU_VAL * __builtin_amdgcn_rcpf(csm);
    if (sub == 0) sv[row] = Bnew;
    __syncthreads();   // B2 (LDS only)
  }

  // ---- epilogue: wd for the final iteration ----
  {
    float x0 = sv[rcol[0]] * rw[0];
    float x1 = sv[rcol[1]] * rw[1];
    float x2 = sv[rcol[2]] * rw[2];
    float x3 = sv[rcol[3]] * rw[3];
    float wsum = x0*rc2[0] + x1*rc2[1] + x2*rc2[2] + x3*rc2[3];
    for (int idx = rOv; idx < re; idx += 4){
      float cv = gvals[base + idx];
      wsum += sv[gcols[base + idx]] * exp2f(-cv) * cv;
    }
    wsum += fdpp<QXOR1>(wsum); wsum += fdpp<QXOR2>(wsum);
    if (sub == 0) wrow[row] = Aprev * wsum;
    __syncthreads();
    if (tid < 64){
      float w4 = wrow[tid] + wrow[tid + 64] + wrow[tid + 128] + wrow[tid + 192];
      w4 = waveReduceSum(w4);
      if (tid == 0) sWd[MAXIT - 1] = w4 * (EPSF * LN2_F);
    }
    __syncthreads();
  }

  // ---- single bulk dump of histories to global ----
  for (int it = tid; it < MAXIT; it += 1024){
    err_ws[it * N_GRAPHS + g] = sErr[it];
    wd_ws [it * N_GRAPHS + g] = sWd[it];
  }
}

// -------- parallel find-T + final mean (one block, 16 waves) --------
__global__ __launch_bounds__(1024) void k_findT_final(
    const float* __restrict__ err_ws, const float* __restrict__ wd_ws,
    float* __restrict__ out)
{
  __shared__ float sSum[MAXIT];
  __shared__ int Tm1s;
  int tid = threadIdx.x, lane = tid & 63, wid = tid >> 6;
  for (int it = wid; it < MAXIT; it += 16){
    float4 v = *reinterpret_cast<const float4*>(&err_ws[it * N_GRAPHS + lane * 4]);
    float s = v.x + v.y + v.z + v.w;
    s = dppSum64(s);
    if (lane == 63) sSum[it] = s;
  }
  __syncthreads();
  if (tid == 0){
    int t = MAXIT - 1;
    for (int it = 0; it < MAXIT; ++it){
      if (sSum[it] * (1.0f / 256.0f) < 0.1f){ t = it; break; }
    }
    Tm1s = t;
  }
  __syncthreads();
  if (wid == 0){
    float4 v = *reinterpret_cast<const float4*>(&wd_ws[Tm1s * N_GRAPHS + lane * 4]);
    float s = v.x + v.y + v.z + v.w;
    s = dppSum64(s);
    if (lane == 63) out[0] = 0.5f * s / 256.0f;
  }
}

extern "C" void kernel_launch(void* const* d_in, const int* in_sizes, int n_in,
                              void* d_out, int out_size, void* d_ws, size_t ws_size,
                              hipStream_t stream)
{
  const float* src = (const float*)d_in[0];
  const float* tgt = (const float*)d_in[1];
  const int*   ei  = (const int*)d_in[2];

  char* ws = (char*)d_ws;
  size_t off = 0;
  auto alloc = [&](size_t bytes) -> char* {
    char* p = ws + off;
    off += (bytes + 255) & ~(size_t)255;
    return p;
  };
  unsigned*       bm     = (unsigned*)      alloc((size_t)N_GRAPHS * 2048 * 4);
  float*          gvals  = (float*)         alloc((size_t)N_GRAPHS * CAP * 4);
  unsigned char*  gcols  = (unsigned char*) alloc((size_t)N_GRAPHS * CAP);
  unsigned char*  grows  = (unsigned char*) alloc((size_t)N_GRAPHS * CAP);
  unsigned short* gcidx  = (unsigned short*)alloc((size_t)N_GRAPHS * CAP * 2);
  int*            grp    = (int*)           alloc((size_t)N_GRAPHS * 257 * 4);
  int*            gcp    = (int*)           alloc((size_t)N_GRAPHS * 257 * 4);
  float*          err_ws = (float*)         alloc((size_t)MAXIT * N_GRAPHS * 4);
  float*          wd_ws  = (float*)         alloc((size_t)MAXIT * N_GRAPHS * 4);

  (void)hipFuncSetAttribute((const void*)k_prep,
                            hipFuncAttributeMaxDynamicSharedMemorySize,
                            DYN_SIZE);

  (void)hipMemsetAsync(bm, 0, (size_t)N_GRAPHS * 2048 * 4, stream);
  k_scatter<<<(N_EDGES + N_NODES + 255) / 256, 256, 0, stream>>>(ei, bm);
  k_prep<<<N_GRAPHS, 1024, DYN_SIZE, stream>>>(bm, src, tgt, gvals, gcols, grows,
                                               gcidx, grp, gcp);
  k_sink<<<N_GRAPHS, 1024, 0, stream>>>(gvals, gcols, grows, gcidx, grp, gcp,
                                        err_ws, wd_ws);
  k_findT_final<<<1, 1024, 0, stream>>>(err_ws, wd_ws, (float*)d_out);
}

// Round 15
// 215.379 us; speedup vs baseline: 1.4810x; 1.4810x over previous
//
#include <hip/hip_runtime.h>

// Problem constants (fixed by reference setup_inputs)
#define N_NODES  65536
#define D_FEAT   256
#define N_GRAPHS 256
#define NPG      256
#define N_EDGES  524288
#define CAPX     2560     // support cap (true max = 2048 edges + 256 diag = 2304)
#define EPSF     0.1f
#define MAXIT    100
#define KMAX     4        // sink register slots per sub-thread; 4 subs -> 16/row
#define LOG2E_F  1.4426950408889634f
#define LN2_F    0.6931471805599453f
#define CSCALE   (10.0f * LOG2E_F)   // C * (1/eps) * log2(e) -> base-2 domain
#define MU_VAL   (1.0f / 256.0f + 1e-8f)

// dynamic LDS region (131072 B), time-multiplexed:
//   phase A: m (8 KB) + sc (1 KB)
//   phase B/C: tgtb = 256 rows x 512 B bf16 (XOR-swizzled)
//   epilogue: strip = 128 rows x 256 f32
#define DYN_SIZE  131072

typedef __attribute__((ext_vector_type(8))) short short8;
typedef __attribute__((ext_vector_type(4))) float f32x4;
union U8 { unsigned u[4]; short8 v; };

__device__ __forceinline__ float waveReduceSum(float v){
  for (int o = 32; o; o >>= 1) v += __shfl_down(v, o);
  return v;
}
template<int CTRL>
__device__ __forceinline__ float fdpp(float x){
  int xi = __float_as_int(x);
  int i = __builtin_amdgcn_update_dpp(xi, xi, CTRL, 0xf, 0xf, true);
  return __int_as_float(i);
}
__device__ __forceinline__ float dppSum64(float x){
  x += fdpp<0x111>(x);
  x += fdpp<0x112>(x);
  x += fdpp<0x114>(x);
  x += fdpp<0x118>(x);
  x += fdpp<0x142>(x);
  x += fdpp<0x143>(x);
  return x;
}
__device__ __forceinline__ float bcast63(float x){
  return __int_as_float(__builtin_amdgcn_readlane(__float_as_int(x), 63));
}
#define QXOR1 0xB1
#define QXOR2 0x4E

// round-to-nearest-even f32 -> bf16 (u16 in low bits)
__device__ __forceinline__ unsigned bf16r(float f){
  unsigned u = __float_as_uint(f);
  return (u + 0x7FFFu + ((u >> 16) & 1u)) >> 16;
}

// -------- scatter edges + diagonal into per-graph bitmask --------
__global__ __launch_bounds__(256) void k_scatter(const int* __restrict__ ei,
                                                 unsigned* __restrict__ bm){
  int t = blockIdx.x * 256 + threadIdx.x;
  if (t < N_EDGES){
    int uu = ei[t], vv = ei[N_EDGES + t];
    int b = uu >> 8;
    int r = uu & 255;
    int c = vv & 255;
    atomicOr(&bm[(size_t)b * 2048 + r * 8 + (c >> 5)], 1u << (c & 31));
  } else {
    int i = t - N_EDGES;
    if (i < N_NODES){
      int b = i >> 8; int p = i & 255;
      atomicOr(&bm[(size_t)b * 2048 + p * 8 + (p >> 5)], 1u << (p & 31));
    }
  }
}

// ==================== fused per-graph kernel ====================
// A: CSR/CSC structure in LDS (unchanged)
// B: norms; tgt -> normalized bf16 (swizzled) in LDS; src norms -> isrow
// C: DENSE cosine via MFMA (A-frags in regs, B-frags from LDS), spill
//    f32 strips into dead tgtb region (2 stages), gather support -> cs[]
// D: Sinkhorn (multiplicative domain) — verbatim R12
__global__ __launch_bounds__(1024) void k_graph(
    const unsigned* __restrict__ bm,
    const float* __restrict__ src, const float* __restrict__ tgt,
    float* __restrict__ err_ws, float* __restrict__ wd_ws)
{
  __shared__ float          cs[CAPX];
  __shared__ unsigned short ents[CAPX];
  __shared__ unsigned short cidx[CAPX];
  __shared__ int            rp[257], cp[257];
  __shared__ float          su[256], sv[256], drow[256], wrow[256];
  __shared__ float          sErr[MAXIT], sWd[MAXIT];
  __shared__ float          isrow[256];
  extern __shared__ char    dyn[];
  uint2*    tgtb = (uint2*)dyn;
  unsigned* m    = (unsigned*)dyn;
  int*      sc   = (int*)(dyn + 8192);
  float*    strip = (float*)dyn;

  int g = blockIdx.x, tid = threadIdx.x;
  int lane = tid & 63, wid = tid >> 6;

  // ---------- Phase A: structure (unchanged from R12) ----------
  for (int i = tid; i < 2048; i += 1024) m[i] = bm[(size_t)g * 2048 + i];
  __syncthreads();

  int nnz = 0;
  if (tid < 256){
    #pragma unroll
    for (int w = 0; w < 8; w++) nnz += __popc(m[tid * 8 + w]);
    sc[tid] = nnz;
  }
  __syncthreads();
  for (int o = 1; o < 256; o <<= 1){
    int t = (tid < 256 && tid >= o) ? sc[tid - o] : 0;
    __syncthreads();
    if (tid < 256) sc[tid] += t;
    __syncthreads();
  }
  if (tid < 256){
    rp[tid] = sc[tid] - nnz;
    if (tid == 255) rp[256] = (sc[255] > CAPX ? CAPX : sc[255]);
  }
  __syncthreads();

  if (tid < 256){
    int k = rp[tid];
    #pragma unroll
    for (int w = 0; w < 8; w++){
      unsigned bits = m[tid * 8 + w];
      while (bits){
        int b = __ffs(bits) - 1; bits &= bits - 1;
        if (k < CAPX) ents[k] = (unsigned short)((tid << 8) | (w * 32 + b));
        k++;
      }
    }
  }
  __syncthreads();

  int cn = 0, cw_ = 0; unsigned cb_ = 0;
  if (tid < 256){
    cw_ = tid >> 5; cb_ = 1u << (tid & 31);
    for (int r = 0; r < 256; r++) cn += (m[r * 8 + cw_] & cb_) ? 1 : 0;
    sc[tid] = cn;
  }
  __syncthreads();
  for (int o = 1; o < 256; o <<= 1){
    int t = (tid < 256 && tid >= o) ? sc[tid - o] : 0;
    __syncthreads();
    if (tid < 256) sc[tid] += t;
    __syncthreads();
  }
  if (tid < 256){
    cp[tid] = sc[tid] - cn;
    if (tid == 255) cp[256] = (sc[255] > CAPX ? CAPX : sc[255]);
  }
  __syncthreads();
  if (tid < 256){
    int kk = cp[tid];
    for (int r = 0; r < 256; r++){
      if (m[r * 8 + cw_] & cb_){
        int idx = rp[r];
        #pragma unroll
        for (int w = 0; w < 8; w++){
          unsigned mm2 = m[r * 8 + w];
          if (w < cw_) idx += __popc(mm2);
          else if (w == cw_) idx += __popc(mm2 & (cb_ - 1u));
        }
        if (kk < CAPX && idx < CAPX) cidx[kk] = (unsigned short)idx;
        kk++;
      }
    }
  }
  __syncthreads();   // m/sc dead; tgtb region free

  // ---------- Phase B: tgt -> swizzled bf16 in LDS; src norms ----------
  const float4* tbase = reinterpret_cast<const float4*>(tgt + (size_t)g * NPG * D_FEAT);
  const float4* sbase = reinterpret_cast<const float4*>(src + (size_t)g * NPG * D_FEAT);
  for (int r = wid; r < 256; r += 16){
    float4 x = tbase[r * 64 + lane];
    float s = x.x*x.x + x.y*x.y + x.z*x.z + x.w*x.w;
    float inv = 1.0f / (sqrtf(bcast63(dppSum64(s))) + 1e-12f);
    unsigned p0 = bf16r(x.x * inv) | (bf16r(x.y * inv) << 16);
    unsigned p1 = bf16r(x.z * inv) | (bf16r(x.w * inv) << 16);
    // XOR swizzle on 8-byte granules: bits[3:5] ^= (r&7)
    tgtb[r * 64 + (lane ^ (r & 7))] = make_uint2(p0, p1);
    float4 y = sbase[r * 64 + lane];
    float s2 = y.x*y.x + y.y*y.y + y.z*y.z + y.w*y.w;
    s2 = dppSum64(s2);
    if (lane == 63) isrow[r] = 1.0f / (sqrtf(s2) + 1e-12f);
  }
  __syncthreads();

  // ---------- Phase C: dense cosine via MFMA ----------
  // A-frag (16x32, bf16): lane l elem j -> m=l&15, k=(l>>4)*4+(j&3)+16*(j>>2)
  // B-frag (32x16): n=l&15, same k mapping.  D: col=lane&15, row=(lane>>4)*4+reg.
  int G = lane >> 4;
  int l7 = lane & 7;
  int myrow = wid * 16 + (lane & 15);
  float is = isrow[myrow];
  const float4* srow = sbase + myrow * 64;
  U8 af[8];
  #pragma unroll
  for (int kk = 0; kk < 8; kk++){
    float4 a0 = srow[kk * 8 + G];        // dims kk*32 + G*4 .. +3
    float4 a1 = srow[kk * 8 + G + 4];    // dims kk*32 + 16 + G*4 .. +3
    af[kk].u[0] = bf16r(a0.x * is) | (bf16r(a0.y * is) << 16);
    af[kk].u[1] = bf16r(a0.z * is) | (bf16r(a0.w * is) << 16);
    af[kk].u[2] = bf16r(a1.x * is) | (bf16r(a1.y * is) << 16);
    af[kk].u[3] = bf16r(a1.z * is) | (bf16r(a1.w * is) << 16);
  }

  int lane_off  = (G * 8) ^ (l7 * 8);          // swizzled offset, elems j0-3
  int lane_off2 = (32 + G * 8) ^ (l7 * 8);     // swizzled offset, elems j4-7
  f32x4 acc[16];
  #pragma unroll
  for (int nt = 0; nt < 16; nt++) acc[nt] = (f32x4){0.f, 0.f, 0.f, 0.f};

  #pragma unroll
  for (int nt = 0; nt < 16; nt++){
    int n = nt * 16 + (lane & 15);
    int rowbyte = n << 9;
    f32x4 a = acc[nt];
    #pragma unroll
    for (int kk = 0; kk < 8; kk++){
      uint2 b0 = *reinterpret_cast<const uint2*>(dyn + rowbyte + kk * 64 + lane_off);
      uint2 b1 = *reinterpret_cast<const uint2*>(dyn + rowbyte + kk * 64 + lane_off2);
      U8 bf;
      bf.u[0] = b0.x; bf.u[1] = b0.y; bf.u[2] = b1.x; bf.u[3] = b1.y;
      a = __builtin_amdgcn_mfma_f32_16x16x32_bf16(af[kk].v, bf.v, a, 0, 0, 0);
    }
    acc[nt] = a;
  }
  __syncthreads();   // all MFMAs done; tgtb dead -> strip region free

  // ---------- spill strips + gather support entries ----------
  int total = rp[256];
  int half_end = rp[128];
  if (wid < 8){
    #pragma unroll
    for (int nt = 0; nt < 16; nt++){
      #pragma unroll
      for (int reg = 0; reg < 4; reg++){
        int rl = wid * 16 + G * 4 + reg;
        strip[rl * 256 + nt * 16 + (lane & 15)] = acc[nt][reg];
      }
    }
  }
  __syncthreads();
  for (int e = tid; e < half_end; e += 1024){
    int r = ents[e] >> 8, c = ents[e] & 255;
    cs[e] = (1.0f - strip[r * 256 + c]) * CSCALE;
  }
  __syncthreads();
  if (wid >= 8){
    #pragma unroll
    for (int nt = 0; nt < 16; nt++){
      #pragma unroll
      for (int reg = 0; reg < 4; reg++){
        int rl = (wid - 8) * 16 + G * 4 + reg;
        strip[rl * 256 + nt * 16 + (lane & 15)] = acc[nt][reg];
      }
    }
  }
  __syncthreads();
  for (int e = half_end + tid; e < total; e += 1024){
    int r = (ents[e] >> 8) - 128, c = ents[e] & 255;
    cs[e] = (1.0f - strip[r * 256 + c]) * CSCALE;
  }
  __syncthreads();

  // ---------- Phase D: Sinkhorn (multiplicative domain, R12 verbatim) ----------
  int row = tid >> 2, sub = tid & 3;

  int rs = rp[row], re = rp[row + 1];
  int rcol[KMAX]; float rw[KMAX], rc2[KMAX];
  #pragma unroll
  for (int k = 0; k < KMAX; k++){
    int idx = rs + sub + 4 * k;
    bool v = idx < re;
    int ai = v ? idx : 0;
    rcol[k] = v ? (ents[ai] & 255) : 0;
    float c2 = v ? cs[ai] : 0.f;
    rw[k]  = v ? exp2f(-c2) : 0.f;
    rc2[k] = c2;
  }
  int rOv = rs + sub + 4 * KMAX;

  int cs0 = cp[row], ce = cp[row + 1];
  int crow[KMAX]; float cw[KMAX];
  #pragma unroll
  for (int k = 0; k < KMAX; k++){
    int idx = cs0 + sub + 4 * k;
    bool v = idx < ce;
    int ai = v ? idx : 0;
    int e = v ? (int)cidx[ai] : 0;
    crow[k] = v ? (ents[e] >> 8) : 0;
    cw[k]   = v ? exp2f(-cs[e]) : 0.f;
  }
  int cOv = cs0 + sub + 4 * KMAX;

  if (tid < 256){ su[tid] = 1.f; sv[tid] = 1.f; }
  __syncthreads();

  const float LOG2_MU = log2f(MU_VAL);
  float a = 0.f, Aprev = 1.f;

  for (int it = 0; it < MAXIT; ++it){
    float x0 = sv[rcol[0]] * rw[0];
    float x1 = sv[rcol[1]] * rw[1];
    float x2 = sv[rcol[2]] * rw[2];
    float x3 = sv[rcol[3]] * rw[3];
    float sm   = x0 + x1 + x2 + x3;
    float wsum = x0*rc2[0] + x1*rc2[1] + x2*rc2[2] + x3*rc2[3];
    for (int idx = rOv; idx < re; idx += 4){
      float cv = cs[idx];
      float xo = sv[ents[idx] & 255] * exp2f(-cv);
      sm += xo; wsum += xo * cv;
    }
    sm   += fdpp<QXOR1>(sm);   sm   += fdpp<QXOR2>(sm);
    wsum += fdpp<QXOR1>(wsum); wsum += fdpp<QXOR2>(wsum);
    float Anew = MU_VAL * __builtin_amdgcn_rcpf(sm);
    float an   = LOG2_MU - __builtin_amdgcn_logf(sm);
    if (sub == 0){
      su[row]   = Anew;
      drow[row] = fabsf(an - a);
      wrow[row] = Aprev * wsum;
    }
    a = an; Aprev = Anew;
    __syncthreads();

    if (tid < 64){
      float e4 = drow[tid] + drow[tid + 64] + drow[tid + 128] + drow[tid + 192];
      e4 = dppSum64(e4);
      if (lane == 63) sErr[it] = e4 * (EPSF * LN2_F);
    } else if (tid < 128 && it > 0){
      int l = tid - 64;
      float w4 = wrow[l] + wrow[l + 64] + wrow[l + 128] + wrow[l + 192];
      w4 = dppSum64(w4);
      if (lane == 63) sWd[it - 1] = w4 * (EPSF * LN2_F);
    }

    float y0 = su[crow[0]] * cw[0];
    float y1 = su[crow[1]] * cw[1];
    float y2 = su[crow[2]] * cw[2];
    float y3 = su[crow[3]] * cw[3];
    float csm = y0 + y1 + y2 + y3;
    for (int idx = cOv; idx < ce; idx += 4){
      int e = cidx[idx];
      csm += su[ents[e] >> 8] * exp2f(-cs[e]);
    }
    csm += fdpp<QXOR1>(csm); csm += fdpp<QXOR2>(csm);
    float Bnew = MU_VAL * __builtin_amdgcn_rcpf(csm);
    if (sub == 0) sv[row] = Bnew;
    __syncthreads();
  }

  {
    float x0 = sv[rcol[0]] * rw[0];
    float x1 = sv[rcol[1]] * rw[1];
    float x2 = sv[rcol[2]] * rw[2];
    float x3 = sv[rcol[3]] * rw[3];
    float wsum = x0*rc2[0] + x1*rc2[1] + x2*rc2[2] + x3*rc2[3];
    for (int idx = rOv; idx < re; idx += 4){
      float cv = cs[idx];
      wsum += sv[ents[idx] & 255] * exp2f(-cv) * cv;
    }
    wsum += fdpp<QXOR1>(wsum); wsum += fdpp<QXOR2>(wsum);
    if (sub == 0) wrow[row] = Aprev * wsum;
    __syncthreads();
    if (tid < 64){
      float w4 = wrow[tid] + wrow[tid + 64] + wrow[tid + 128] + wrow[tid + 192];
      w4 = dppSum64(w4);
      if (lane == 63) sWd[MAXIT - 1] = w4 * (EPSF * LN2_F);
    }
    __syncthreads();
  }

  for (int it = tid; it < MAXIT; it += 1024){
    err_ws[it * N_GRAPHS + g] = sErr[it];
    wd_ws [it * N_GRAPHS + g] = sWd[it];
  }
}

// -------- parallel find-T + final mean (one block, 16 waves) --------
__global__ __launch_bounds__(1024) void k_findT_final(
    const float* __restrict__ err_ws, const float* __restrict__ wd_ws,
    float* __restrict__ out)
{
  __shared__ float sSum[MAXIT];
  __shared__ int Tm1s;
  int tid = threadIdx.x, lane = tid & 63, wid = tid >> 6;
  for (int it = wid; it < MAXIT; it += 16){
    float4 v = *reinterpret_cast<const float4*>(&err_ws[it * N_GRAPHS + lane * 4]);
    float s = v.x + v.y + v.z + v.w;
    s = dppSum64(s);
    if (lane == 63) sSum[it] = s;
  }
  __syncthreads();
  if (tid == 0){
    int t = MAXIT - 1;
    for (int it = 0; it < MAXIT; ++it){
      if (sSum[it] * (1.0f / 256.0f) < 0.1f){ t = it; break; }
    }
    Tm1s = t;
  }
  __syncthreads();
  if (wid == 0){
    float4 v = *reinterpret_cast<const float4*>(&wd_ws[Tm1s * N_GRAPHS + lane * 4]);
    float s = v.x + v.y + v.z + v.w;
    s = dppSum64(s);
    if (lane == 63) out[0] = 0.5f * s / 256.0f;
  }
}

extern "C" void kernel_launch(void* const* d_in, const int* in_sizes, int n_in,
                              void* d_out, int out_size, void* d_ws, size_t ws_size,
                              hipStream_t stream)
{
  const float* src = (const float*)d_in[0];
  const float* tgt = (const float*)d_in[1];
  const int*   ei  = (const int*)d_in[2];

  char* ws = (char*)d_ws;
  size_t off = 0;
  auto alloc = [&](size_t bytes) -> char* {
    char* p = ws + off;
    off += (bytes + 255) & ~(size_t)255;
    return p;
  };
  unsigned* bm     = (unsigned*) alloc((size_t)N_GRAPHS * 2048 * 4);
  float*    err_ws = (float*)    alloc((size_t)MAXIT * N_GRAPHS * 4);
  float*    wd_ws  = (float*)    alloc((size_t)MAXIT * N_GRAPHS * 4);

  (void)hipFuncSetAttribute((const void*)k_graph,
                            hipFuncAttributeMaxDynamicSharedMemorySize,
                            DYN_SIZE);

  (void)hipMemsetAsync(bm, 0, (size_t)N_GRAPHS * 2048 * 4, stream);
  k_scatter<<<(N_EDGES + N_NODES + 255) / 256, 256, 0, stream>>>(ei, bm);
  k_graph<<<N_GRAPHS, 1024, DYN_SIZE, stream>>>(bm, src, tgt, err_ws, wd_ws);
  k_findT_final<<<1, 1024, 0, stream>>>(err_ws, wd_ws, (float*)d_out);
}